// Round 13
// baseline (2244.996 us; speedup 1.0000x reference)
//
#include <hip/hip_runtime.h>
#include <math.h>

#define D_MODEL 512
#define NHEAD   8
#define NLAYER  6
#define DFF_    2048
#define VOCAB   32000
#define BATCH   2
#define SEQ     2048
#define NTOK    (BATCH*SEQ)
#define PAD_ID  1

typedef __attribute__((ext_vector_type(8))) short s16x8;
typedef __attribute__((ext_vector_type(4))) float f32x4;
typedef unsigned short u16;
typedef unsigned int   u32;
typedef unsigned long long u64;

__device__ __forceinline__ u16 f2bf(float x) {
  u32 u = __builtin_bit_cast(u32, x);
  u += 0x7FFFu + ((u >> 16) & 1u);
  return (u16)(u >> 16);
}

__device__ __forceinline__ float exp2i(float x) {
  float r; asm("v_exp_f32 %0, %1" : "=v"(r) : "v"(x)); return r;
}

__device__ __forceinline__ void gload16(const void* g, void* l) {
  __builtin_amdgcn_global_load_lds(
      (const __attribute__((address_space(1))) u32*)g,
      (__attribute__((address_space(3))) u32*)l, 16, 0, 0);
}

#define CEXP 0.1803368802f   /* 0.125 * log2(e) */

// ------------------------------------------------------------------ embed both streams (z = 0 src, 1 tgt)
__global__ __launch_bounds__(256) void embed2_kernel(
    const int* __restrict__ src, const int* __restrict__ tgt,
    const float* __restrict__ se, const float* __restrict__ te,
    const float* __restrict__ pe, float* __restrict__ xe, float* __restrict__ yd)
{
  const int z = blockIdx.y;
  const int* tok = z ? tgt : src;
  const float* emb = z ? te : se;
  float* out = z ? yd : xe;
  const int total = NTOK * D_MODEL;
  for (int i = blockIdx.x * 256 + threadIdx.x; i < total; i += gridDim.x * 256) {
    int t = i >> 9;
    int d = i & 511;
    int s = t & (SEQ - 1);
    out[i] = emb[(size_t)tok[t] * D_MODEL + d] + pe[(size_t)s * D_MODEL + d];
  }
}

// ------------------------------------------------------------------ pad masks for both token streams
__global__ __launch_bounds__(64) void padmask2_kernel(
    const int* __restrict__ src, const int* __restrict__ tgt,
    u64* __restrict__ pmS, u64* __restrict__ pmT)
{
  const int z = blockIdx.z;
  const int* tok = z ? tgt : src;
  u64* pm = z ? pmT : pmS;
  int b = blockIdx.y, t = blockIdx.x;
  int lane = threadIdx.x;
  u64 m = __ballot(tok[(size_t)b * SEQ + t * 64 + lane] != PAD_ID);
  if (lane == 0) pm[b * (SEQ / 64) + t] = m;
}

// ------------------------------------------------------------------ layernorm: one wave per row, shuffle-only
__global__ __launch_bounds__(256) void ln_kernel(
    const float* __restrict__ x, const float* __restrict__ g,
    const float* __restrict__ bb, u16* __restrict__ y)
{
  const int lane = threadIdx.x & 63;
  const size_t row = (size_t)blockIdx.x * 4 + (threadIdx.x >> 6);
  const float* xr = x + row * D_MODEL + lane * 8;
  float4 v0 = *(const float4*)xr;
  float4 v1 = *(const float4*)(xr + 4);
  float sum = (v0.x + v0.y) + (v0.z + v0.w) + (v1.x + v1.y) + (v1.z + v1.w);
  float ss = v0.x * v0.x + v0.y * v0.y + v0.z * v0.z + v0.w * v0.w
           + v1.x * v1.x + v1.y * v1.y + v1.z * v1.z + v1.w * v1.w;
  #pragma unroll
  for (int o = 1; o < 64; o <<= 1) {
    sum += __shfl_xor(sum, o, 64);
    ss  += __shfl_xor(ss, o, 64);
  }
  float mean = sum * (1.0f / D_MODEL);
  float inv = rsqrtf(ss * (1.0f / D_MODEL) - mean * mean + 1e-5f);
  float4 g0 = *(const float4*)&g[lane * 8];
  float4 g1 = *(const float4*)&g[lane * 8 + 4];
  float4 c0 = *(const float4*)&bb[lane * 8];
  float4 c1 = *(const float4*)&bb[lane * 8 + 4];
  uint4 o;
  o.x = (u32)f2bf((v0.x - mean) * inv * g0.x + c0.x) | ((u32)f2bf((v0.y - mean) * inv * g0.y + c0.y) << 16);
  o.y = (u32)f2bf((v0.z - mean) * inv * g0.z + c0.z) | ((u32)f2bf((v0.w - mean) * inv * g0.w + c0.w) << 16);
  o.z = (u32)f2bf((v1.x - mean) * inv * g1.x + c1.x) | ((u32)f2bf((v1.y - mean) * inv * g1.y + c1.y) << 16);
  o.w = (u32)f2bf((v1.z - mean) * inv * g1.z + c1.z) | ((u32)f2bf((v1.w - mean) * inv * g1.w + c1.w) << 16);
  *(uint4*)&y[row * D_MODEL + lane * 8] = o;
}

// ------------------------------------------------------------------ transpose+convert, two-source: f32 [K][N] -> bf16 [N][K]
__global__ __launch_bounds__(256) void tconv2_kernel(
    const float* __restrict__ s0, const float* __restrict__ s1,
    u16* __restrict__ d0, u16* __restrict__ d1, int zsplit, int K, int N)
{
  __shared__ float tile[64][65];
  const int z = blockIdx.z;
  const float* src = (z < zsplit) ? s0 + (size_t)z * K * N : s1 + (size_t)(z - zsplit) * K * N;
  u16* dst = (z < zsplit) ? d0 + (size_t)z * K * N : d1 + (size_t)(z - zsplit) * K * N;
  const int n0 = blockIdx.x * 64, k0 = blockIdx.y * 64;
  const int t = threadIdx.x;
  const int cr = t >> 4, cc = (t & 15) * 4;
  #pragma unroll
  for (int it = 0; it < 4; ++it) {
    int kr = cr + it * 16;
    float4 v = *(const float4*)&src[(size_t)(k0 + kr) * N + n0 + cc];
    tile[kr][cc] = v.x; tile[kr][cc + 1] = v.y; tile[kr][cc + 2] = v.z; tile[kr][cc + 3] = v.w;
  }
  __syncthreads();
  #pragma unroll
  for (int it = 0; it < 4; ++it) {
    int nr = cr + it * 16;
    u32 lo = (u32)f2bf(tile[cc + 0][nr]) | ((u32)f2bf(tile[cc + 1][nr]) << 16);
    u32 hi = (u32)f2bf(tile[cc + 2][nr]) | ((u32)f2bf(tile[cc + 3][nr]) << 16);
    uint2 pk; pk.x = lo; pk.y = hi;
    *(uint2*)&dst[(size_t)(n0 + nr) * K + k0 + cc] = pk;
  }
}

// ------------------------------------------------------------------ transpose+convert, three-source 512x512 (z: 0-23 s0, 24-47 s1, 48-71 s2)
__global__ __launch_bounds__(256) void tconv3_kernel(
    const float* __restrict__ s0, const float* __restrict__ s1,
    const float* __restrict__ s2, u16* __restrict__ dst0)
{
  __shared__ float tile[64][65];
  const int z = blockIdx.z;
  const float* src = (z < 24) ? s0 + (size_t)z * 262144
                   : (z < 48) ? s1 + (size_t)(z - 24) * 262144
                              : s2 + (size_t)(z - 48) * 262144;
  u16* dst = dst0 + (size_t)z * 262144;
  const int n0 = blockIdx.x * 64, k0 = blockIdx.y * 64;
  const int t = threadIdx.x;
  const int cr = t >> 4, cc = (t & 15) * 4;
  #pragma unroll
  for (int it = 0; it < 4; ++it) {
    int kr = cr + it * 16;
    float4 v = *(const float4*)&src[(size_t)(k0 + kr) * 512 + n0 + cc];
    tile[kr][cc] = v.x; tile[kr][cc + 1] = v.y; tile[kr][cc + 2] = v.z; tile[kr][cc + 3] = v.w;
  }
  __syncthreads();
  #pragma unroll
  for (int it = 0; it < 4; ++it) {
    int nr = cr + it * 16;
    u32 lo = (u32)f2bf(tile[cc + 0][nr]) | ((u32)f2bf(tile[cc + 1][nr]) << 16);
    u32 hi = (u32)f2bf(tile[cc + 2][nr]) | ((u32)f2bf(tile[cc + 3][nr]) << 16);
    uint2 pk; pk.x = lo; pk.y = hi;
    *(uint2*)&dst[(size_t)(n0 + nr) * 512 + k0 + cc] = pk;
  }
}

// ------------------------------------------------------------------ bf16 MFMA GEMM: C[M,N] = A[M,K] @ Wt[N,K]^T + bias
// MODE 0: f32 out, 1: f32 out + res, 2: bf16 out, 3: bf16 out + relu,
// MODE 4: qkv (z==2 -> V-transpose into vtOut), 5: crosskv (MAP=1; odd z -> vtrans),
// MODE 6: f32 out + res + bf16 row-major copy into vtOut
// DB (BM+BN<=256): double-buffered LDS, 1 barrier/K-step.
// XSWAP: blockIdx.x indexes M (consecutive blocks share the B-tile).
template<int MODE, int BM, int BN, int MAP, int XSWAP = 0>
__global__ __launch_bounds__(256, 2) void mm_kernel(
    const u16* __restrict__ A, const u16* __restrict__ Wt,
    const float* __restrict__ bias, const float* __restrict__ res,
    void* __restrict__ Cout, u16* __restrict__ vtOut,
    int M, int N, int K,
    long long wStride, long long bStride, long long cStride)
{
  constexpr int MI = BM / 32;
  constexpr int NI = (BN + 31) / 32;          // 1 for BN=32
  constexpr int NFRAG = (BN >= 32) ? NI : 1;
  constexpr bool DB = (BM + BN <= 256);
  __shared__ u16 sh[(DB ? 2 : 1) * (BM + BN) * 64];
  const int z = blockIdx.z;
  size_t wOff, bOff;
  if (MAP == 1) {
    wOff = (size_t)(z >> 1) * 4 * 262144 + (size_t)(1 + (z & 1)) * 262144;
    bOff = (size_t)(z >> 1) * 4 * 512 + (size_t)(1 + (z & 1)) * 512;
  } else {
    wOff = (size_t)z * wStride;
    bOff = (size_t)z * bStride;
  }
  Wt += wOff;
  bias += bOff;
  const int bm = (XSWAP ? blockIdx.x : blockIdx.y) * BM;
  const int bn = (XSWAP ? blockIdx.y : blockIdx.x) * BN;
  const int tid = threadIdx.x, lane = tid & 63, w = tid >> 6;
  const int wm = w >> 1, wn = w & 1;
  const int l15 = lane & 15, l4 = lane >> 4;
  const int wrow0 = wm * (BM / 2), wcol0 = wn * (BN / 2);
  const u16* aBase = A  + (size_t)bm * K;
  const u16* bBase = Wt + (size_t)bn * K;
  f32x4 acc[MI][NFRAG] = {};

  auto mfma_step = [&](const u16* Asb, const u16* Bsb) {
    #pragma unroll
    for (int ks = 0; ks < 2; ++ks) {
      s16x8 af[MI], bf[NFRAG];
      #pragma unroll
      for (int mi = 0; mi < MI; ++mi) {
        int rr = wrow0 + mi * 16 + l15;
        af[mi] = *(const s16x8*)&Asb[(rr << 6) + (((ks * 4 + l4) ^ (rr & 7)) << 3)];
      }
      #pragma unroll
      for (int ni = 0; ni < NFRAG; ++ni) {
        int rr = wcol0 + ni * 16 + l15;
        bf[ni] = *(const s16x8*)&Bsb[(rr << 6) + (((ks * 4 + l4) ^ (rr & 7)) << 3)];
      }
      #pragma unroll
      for (int mi = 0; mi < MI; ++mi)
        #pragma unroll
        for (int ni = 0; ni < NFRAG; ++ni)
          acc[mi][ni] = __builtin_amdgcn_mfma_f32_16x16x32_bf16(af[mi], bf[ni], acc[mi][ni], 0, 0, 0);
    }
  };

  if constexpr (DB) {
    u16* As0 = sh;
    u16* As1 = sh + BM * 64;
    u16* Bs0 = sh + 2 * BM * 64;
    u16* Bs1 = sh + 2 * BM * 64 + BN * 64;
    auto stage = [&](int k0, u16* Ad, u16* Bd) {
      #pragma unroll
      for (int i = 0; i < BM / 32; ++i) {
        int lin = i * 256 + tid;
        int r = lin >> 3, sp = lin & 7;
        gload16(aBase + (size_t)r * K + k0 + ((sp ^ (r & 7)) * 8), &Ad[(i * 256 + w * 64) * 8]);
      }
      if constexpr (BN >= 64) {
        #pragma unroll
        for (int i = 0; i < BN / 32; ++i) {
          int lin = i * 256 + tid;
          int r = lin >> 3, sp = lin & 7;
          gload16(bBase + (size_t)r * K + k0 + ((sp ^ (r & 7)) * 8), &Bd[(i * 256 + w * 64) * 8]);
        }
      } else {
        int r = tid >> 3, sp = tid & 7;   // 256 threads cover 32 rows x 64 k
        gload16(bBase + (size_t)r * K + k0 + ((sp ^ (r & 7)) * 8), &Bd[(w * 64) * 8]);
      }
    };
    stage(0, As0, Bs0);
    __syncthreads();
    const int nt = K >> 6;
    for (int t = 0; t < nt; ++t) {
      const bool even = !(t & 1);
      u16* Ac = even ? As0 : As1;
      u16* Bc = even ? Bs0 : Bs1;
      if (t + 1 < nt) stage((t + 1) << 6, even ? As1 : As0, even ? Bs1 : Bs0);
      mfma_step(Ac, Bc);
      __syncthreads();
    }
  } else {
    u16* As = sh;
    u16* Bs = sh + BM * 64;
    for (int k0 = 0; k0 < K; k0 += 64) {
      #pragma unroll
      for (int i = 0; i < BM / 32; ++i) {
        int lin = i * 256 + tid;
        int r = lin >> 3, sp = lin & 7;
        gload16(aBase + (size_t)r * K + k0 + ((sp ^ (r & 7)) * 8), &As[(i * 256 + w * 64) * 8]);
      }
      #pragma unroll
      for (int i = 0; i < BN / 32; ++i) {
        int lin = i * 256 + tid;
        int r = lin >> 3, sp = lin & 7;
        gload16(bBase + (size_t)r * K + k0 + ((sp ^ (r & 7)) * 8), &Bs[(i * 256 + w * 64) * 8]);
      }
      __syncthreads();
      mfma_step(As, Bs);
      __syncthreads();
    }
  }

  const bool vpath = (MODE == 4 && z == 2) || (MODE == 5 && (z & 1) == 1);
  if (vpath) {
    u16* TT = sh;
    #pragma unroll
    for (int mi = 0; mi < MI; ++mi)
      #pragma unroll
      for (int ni = 0; ni < NFRAG; ++ni)
        #pragma unroll
        for (int r = 0; r < 4; ++r) {
          int rowl = wrow0 + mi * 16 + l4 * 4 + r;
          int coll = wcol0 + ni * 16 + l15;
          TT[coll * 72 + rowl] = f2bf(acc[mi][ni][r] + bias[bn + coll]);
        }
    __syncthreads();
    const int b = bm >> 11, s0loc = bm & 2047, h = bn >> 6;
    const int layer = (MODE == 5) ? (z >> 1) : 0;
    u16* vbase = vtOut + (size_t)layer * ((size_t)NTOK * D_MODEL)
               + ((size_t)(b * NHEAD + h) * 64) * SEQ;
    int d = tid >> 2, sc = (tid & 3) * 16;
    s16x8 v0 = *(const s16x8*)&TT[d * 72 + sc];
    s16x8 v1 = *(const s16x8*)&TT[d * 72 + sc + 8];
    *(s16x8*)(vbase + (size_t)d * SEQ + s0loc + sc) = v0;
    *(s16x8*)(vbase + (size_t)d * SEQ + s0loc + sc + 8) = v1;
    return;
  }

  const int zi = (MAP == 1) ? (z >> 1) : z;
  #pragma unroll
  for (int ni = 0; ni < NFRAG; ++ni) {
    int col = bn + wcol0 + ni * 16 + l15;
    float bb = bias[col];
    #pragma unroll
    for (int mi = 0; mi < MI; ++mi) {
      #pragma unroll
      for (int r = 0; r < 4; ++r) {
        int row = bm + wrow0 + mi * 16 + l4 * 4 + r;
        size_t off = (size_t)zi * cStride + (size_t)row * N + col;
        float v = acc[mi][ni][r] + bb;
        if (MODE == 1 || MODE == 6) v += res[(size_t)row * N + col];
        if (MODE == 3) v = fmaxf(v, 0.0f);
        if (MODE <= 1 || MODE == 6) ((float*)Cout)[off] = v;
        else                        ((u16*)Cout)[off] = f2bf(v);
        if (MODE == 6) vtOut[(size_t)row * N + col] = f2bf(v);
      }
    }
  }
}

// ------------------------------------------------------------------ flash attention, bf16 MFMA
// QBLK=128 (8 waves, 512 threads; wave w owns q-rows qt+16w..+16), KVBLK=128,
// double-buffered K/V. Swapped QK^T: each thread owns one q-row.
template<int CAUSAL, int QPROJ>
__global__ __launch_bounds__(512, 2) void fattn_kernel(
    const u16* __restrict__ Qg, const u16* __restrict__ Kg,
    const u16* __restrict__ Vt, const u16* __restrict__ Wq,
    const float* __restrict__ qbias, const u64* __restrict__ padm,
    u16* __restrict__ Og)
{
  __shared__ u16 Ks[2][128 * 64];
  __shared__ u16 Vs[2][64 * 128];
  __shared__ u16 Ps[8][16 * 128];
  const int qtile = CAUSAL ? (int)(gridDim.x - 1 - blockIdx.x) : (int)blockIdx.x;
  const int qt = qtile * 128;
  const int h = blockIdx.y, b = blockIdx.z;
  const int tid = threadIdx.x, lane = tid & 63, w = tid >> 6;   // w in [0,8)
  const int l15 = lane & 15, l4 = lane >> 4;
  const int hoff = h * 64;
  const u16* Kbase = Kg + (size_t)(b * SEQ) * D_MODEL + hoff;
  const u16* Vbase = Vt + (size_t)(b * NHEAD + h) * 64 * SEQ;
  const u64* pmb = padm + b * (SEQ / 64);
  const int qg = qt + w * 16 + l15;    // this thread's q row

  s16x8 aq[2];
  if constexpr (QPROJ) {
    // Q[128x64] = X[qt..qt+128, :] @ Wq[h*64..+64, :]^T + qbias
    const u16* xBase = Qg + (size_t)(b * SEQ + qt) * D_MODEL;
    const u16* wBase = Wq + (size_t)hoff * D_MODEL;
    u16* Xs  = Ks[0];            // 128x64 = 16 KB
    u16* Wsh = Vs[0];            // 64x64  =  8 KB
    f32x4 qa[4] = {};
    for (int k0 = 0; k0 < 512; k0 += 64) {
      #pragma unroll
      for (int i = 0; i < 2; ++i) {
        int lin = i * 512 + tid;
        int r = lin >> 3, sp = lin & 7;
        gload16(xBase + (size_t)r * D_MODEL + k0 + ((sp ^ (r & 7)) * 8), &Xs[(i * 512 + w * 64) * 8]);
      }
      {
        int r = tid >> 3, sp = tid & 7;
        gload16(wBase + (size_t)r * D_MODEL + k0 + ((sp ^ (r & 7)) * 8), &Wsh[(w * 64) * 8]);
      }
      __syncthreads();
      #pragma unroll
      for (int ks = 0; ks < 2; ++ks) {
        int rr = w * 16 + l15;
        s16x8 xa = *(const s16x8*)&Xs[(rr << 6) + (((ks * 4 + l4) ^ (rr & 7)) << 3)];
        #pragma unroll
        for (int ni = 0; ni < 4; ++ni) {
          int rw = ni * 16 + l15;
          s16x8 wb = *(const s16x8*)&Wsh[(rw << 6) + (((ks * 4 + l4) ^ (rw & 7)) << 3)];
          qa[ni] = __builtin_amdgcn_mfma_f32_16x16x32_bf16(xa, wb, qa[ni], 0, 0, 0);
        }
      }
      __syncthreads();
    }
    // C-layout -> A-layout transpose through swizzled LDS (16 KB of Ps)
    u16* Qsh = (u16*)Ps;
    #pragma unroll
    for (int ni = 0; ni < 4; ++ni) {
      int col = ni * 16 + l15;
      float bb = qbias[hoff + col];
      #pragma unroll
      for (int r = 0; r < 4; ++r) {
        int row = w * 16 + l4 * 4 + r;
        Qsh[(row << 6) + ((((col >> 3)) ^ (row & 7)) << 3) + (col & 7)] = f2bf(qa[ni][r] + bb);
      }
    }
    __syncthreads();
    {
      int rr = w * 16 + l15;
      aq[0] = *(const s16x8*)&Qsh[(rr << 6) + (((0 + l4) ^ (rr & 7)) << 3)];
      aq[1] = *(const s16x8*)&Qsh[(rr << 6) + (((4 + l4) ^ (rr & 7)) << 3)];
    }
  } else {
    const u16* qp = Qg + (size_t)(b * SEQ + qg) * D_MODEL + hoff + l4 * 8;
    aq[0] = *(const s16x8*)qp;
    aq[1] = *(const s16x8*)(qp + 32);
  }

  f32x4 oacc[4] = {};            // oacc[jn][r] = O[q][d = jn*16 + l4*4 + r]
  float mrow = -1e30f, lrow = 0.f;
  const int nt = CAUSAL ? (qt >> 7) + 1 : SEQ / 128;

  #define STAGE(KV0, BUF)                                                              \
    {                                                                                  \
      _Pragma("unroll")                                                                \
      for (int it = 0; it < 2; ++it) {                                                 \
        int lin = it * 512 + tid;                                                      \
        int rr = lin >> 3, sp = lin & 7;                                               \
        gload16(Kbase + (size_t)((KV0) + rr) * D_MODEL + ((sp ^ (rr & 7)) * 8),        \
                &Ks[BUF][(it * 512 + w * 64) * 8]);                                    \
      }                                                                                \
      _Pragma("unroll")                                                                \
      for (int it = 0; it < 2; ++it) {                                                 \
        int lin = it * 512 + tid;                                                      \
        int rr = lin >> 4, ko = lin & 15;                                              \
        gload16(Vbase + (size_t)rr * SEQ + (KV0) + ((ko ^ (rr & 15)) * 8),             \
                &Vs[BUF][(it * 512 + w * 64) * 8]);                                    \
      }                                                                                \
    }

  if constexpr (QPROJ) __syncthreads();   // aq reads done before Ks/Vs/Ps reuse
  STAGE(0, 0);
  __syncthreads();

  for (int kt = 0; kt < nt; ++kt) {
    const int kv0 = kt * 128;
    const int cur = kt & 1;
    if (kt + 1 < nt) STAGE(kv0 + 128, cur ^ 1);

    // S^T[kv][q] = mfma(K, Q): sac[jn][r] -> kv = kv0 + jn*16 + l4*4 + r, q = l15
    f32x4 sac[8] = {};
    __builtin_amdgcn_s_setprio(1);
    #pragma unroll
    for (int ks = 0; ks < 2; ++ks)
      #pragma unroll
      for (int jn = 0; jn < 8; ++jn) {
        int rr = jn * 16 + l15;
        s16x8 ak = *(const s16x8*)&Ks[cur][(rr << 6) + (((ks * 4 + l4) ^ (rr & 7)) << 3)];
        sac[jn] = __builtin_amdgcn_mfma_f32_16x16x32_bf16(ak, aq[ks], sac[jn], 0, 0, 0);
      }
    __builtin_amdgcn_s_setprio(0);

    const u64 m0 = pmb[(kv0 >> 6)];
    const u64 m1 = pmb[(kv0 >> 6) + 1];
    const bool lastC = CAUSAL && (kt == nt - 1);
    if (((m0 & m1) != ~0ull) || lastC) {
      #pragma unroll
      for (int jn = 0; jn < 8; ++jn) {
        u64 mm = (jn < 4) ? m0 : m1;
        #pragma unroll
        for (int r = 0; r < 4; ++r) {
          int kl = (jn & 3) * 16 + l4 * 4 + r;
          int kvg = kv0 + jn * 16 + l4 * 4 + r;
          bool ok = ((mm >> kl) & 1) && (!CAUSAL || kvg <= qg);
          if (!ok) sac[jn][r] = -1e30f;
        }
      }
    }

    // row max: thread-local over 32, then 2 shuffles across l4
    float m = sac[0][0];
    #pragma unroll
    for (int jn = 0; jn < 8; ++jn)
      #pragma unroll
      for (int r = 0; r < 4; ++r) m = fmaxf(m, sac[jn][r]);
    m = fmaxf(m, __shfl_xor(m, 16, 64));
    m = fmaxf(m, __shfl_xor(m, 32, 64));

    if (__any(m - mrow > 64.0f)) {    // defer-max (THR = 8 post-scale)
      float mn = fmaxf(mrow, m);
      float sc = exp2i((mrow - mn) * CEXP);
      mrow = mn;
      lrow *= sc;
      #pragma unroll
      for (int jn = 0; jn < 4; ++jn)
        #pragma unroll
        for (int r = 0; r < 4; ++r) oacc[jn][r] *= sc;
    }

    // P = exp; pack 4 bf16 -> b64 LDS store (swizzled), accumulate row sum
    float rs = 0.f;
    #pragma unroll
    for (int jn = 0; jn < 8; ++jn) {
      float p0 = exp2i((sac[jn][0] - mrow) * CEXP);
      float p1 = exp2i((sac[jn][1] - mrow) * CEXP);
      float p2 = exp2i((sac[jn][2] - mrow) * CEXP);
      float p3 = exp2i((sac[jn][3] - mrow) * CEXP);
      rs += (p0 + p1) + (p2 + p3);
      uint2 pk;
      pk.x = (u32)f2bf(p0) | ((u32)f2bf(p1) << 16);
      pk.y = (u32)f2bf(p2) | ((u32)f2bf(p3) << 16);
      int pu = (jn * 4 + l4) ^ ((l15 & 7) << 2);
      *(uint2*)&Ps[w][l15 * 128 + pu * 4] = pk;
    }
    rs += __shfl_xor(rs, 16, 64);
    rs += __shfl_xor(rs, 32, 64);
    lrow += rs;

    // O^T accumulation: oacc[jn] = mfma(A = V^T[d-block jn], B = P^T)
    __builtin_amdgcn_s_setprio(1);
    #pragma unroll
    for (int ks2 = 0; ks2 < 4; ++ks2) {
      int pu = (ks2 * 8 + l4 * 2) ^ ((l15 & 7) << 2);
      s16x8 pb = *(const s16x8*)&Ps[w][l15 * 128 + pu * 4];
      #pragma unroll
      for (int jn = 0; jn < 4; ++jn) {
        int rr = jn * 16 + l15;
        s16x8 av = *(const s16x8*)&Vs[cur][(rr << 7) + (((ks2 * 4 + l4) ^ (rr & 15)) << 3)];
        oacc[jn] = __builtin_amdgcn_mfma_f32_16x16x32_bf16(av, pb, oacc[jn], 0, 0, 0);
      }
    }
    __builtin_amdgcn_s_setprio(0);
    __syncthreads();
  }
  #undef STAGE

  const float inv = 1.0f / lrow;
  u16* orow = Og + (size_t)(b * SEQ + qg) * D_MODEL + hoff;
  #pragma unroll
  for (int jn = 0; jn < 4; ++jn) {
    uint2 pk;
    pk.x = (u32)f2bf(oacc[jn][0] * inv) | ((u32)f2bf(oacc[jn][1] * inv) << 16);
    pk.y = (u32)f2bf(oacc[jn][2] * inv) | ((u32)f2bf(oacc[jn][3] * inv) << 16);
    *(uint2*)(orow + jn * 16 + l4 * 4) = pk;
  }
}

// ------------------------------------------------------------------ host
extern "C" void kernel_launch(void* const* d_in, const int* in_sizes, int n_in,
                              void* d_out, int out_size, void* d_ws, size_t ws_size,
                              hipStream_t stream)
{
  const int*   src        = (const int*)  d_in[0];
  const int*   tgt        = (const int*)  d_in[1];
  const float* src_emb    = (const float*)d_in[2];
  const float* tgt_emb    = (const float*)d_in[3];
  const float* pe         = (const float*)d_in[4];
  const float* enc_attn_w = (const float*)d_in[5];
  const float* enc_attn_b = (const float*)d_in[6];
  const float* enc_ff_w1  = (const float*)d_in[7];
  const float* enc_ff_b1  = (const float*)d_in[8];
  const float* enc_ff_w2  = (const float*)d_in[9];
  const float* enc_ff_b2  = (const float*)d_in[10];
  const float* enc_ln_g   = (const float*)d_in[11];
  const float* enc_ln_bb  = (const float*)d_in[12];
  const float* dec_self_w = (const float*)d_in[13];
  const float* dec_self_b = (const float*)d_in[14];
  const float* dec_src_w  = (const float*)d_in[15];
  const float* dec_src_b  = (const float*)d_in[16];
  const float* dec_ff_w1  = (const float*)d_in[17];
  const float* dec_ff_b1  = (const float*)d_in[18];
  const float* dec_ff_w2  = (const float*)d_in[19];
  const float* dec_ff_b2  = (const float*)d_in[20];
  const float* dec_ln_g   = (const float*)d_in[21];
  const float* dec_ln_bb  = (const float*)d_in[22];
  const float* fin_ln_g   = (const float*)d_in[23];
  const float* fin_ln_b   = (const float*)d_in[24];
  const float* fc_w       = (const float*)d_in[25];
  const float* fc_b       = (const float*)d_in[26];
  float* out = (float*)d_out;

  const size_t DD = (size_t)D_MODEL * D_MODEL;
  const size_t FD = (size_t)D_MODEL * DFF_;
  const size_t TD = (size_t)NTOK * D_MODEL;

  // ---- scratch in d_out (all dead before the final GEMM writes d_out) ----
  char* ob = (char*)d_out;
  size_t off = 0;
  auto alloco = [&](size_t bytes) { void* p = ob + off; off += (bytes + 255) & ~(size_t)255; return p; };
  u16* wt_enc_attn = (u16*)alloco(24 * DD * 2);
  u16* wt_dec_self = (u16*)alloco(24 * DD * 2);
  u16* wt_dec_src  = (u16*)alloco(24 * DD * 2);
  u16* wt_enc_ff1  = (u16*)alloco(6 * FD * 2);
  u16* wt_enc_ff2  = (u16*)alloco(6 * FD * 2);
  u16* wt_dec_ff1  = (u16*)alloco(6 * FD * 2);
  u16* wt_dec_ff2  = (u16*)alloco(6 * FD * 2);
  u16* qb   = (u16*)alloco(2 * TD * 2);             // q,k contiguous
  u16* kb   = qb + TD;
  u16* vtb  = (u16*)alloco(TD * 2);                 // self-attn V^T [B*H][64][SEQ]
  u16* aob  = (u16*)alloco(TD * 2);
  u16* hbb  = (u16*)alloco((size_t)NTOK * DFF_ * 2);
  u16* memb = (u16*)alloco(TD * 2);
  u16* ckb  = (u16*)alloco(6 * TD * 2);             // cross K, all layers
  u16* cvtb = (u16*)alloco(6 * TD * 2);             // cross V^T, all layers

  // ---- mandatory ws (live during final GEMM) ----
  char* wsb = (char*)d_ws;
  u16*   fcwt = (u16*)wsb;
  size_t wo = ((size_t)VOCAB * D_MODEL * 2 + 255) & ~(size_t)255;
  float* xe  = (float*)(wsb + wo); wo += TD * 4;
  float* yd  = (float*)(wsb + wo); wo += TD * 4;
  u16*   x2b = (u16*)(wsb + wo);   wo += TD * 2;
  u64*   pmS = (u64*)(wsb + wo);   wo += 1024;
  u64*   pmT = (u64*)(wsb + wo);

  dim3 blk(256), blkA(512);
  dim3 gN512(16, 64, 1), gQKV(8, 64, 3), gCKV(8, 64, 12);
  dim3 gFF1(32, 64, 1), gFC(32, 125, 1);
  dim3 gAttn(SEQ / 128, NHEAD, BATCH);
  dim3 gLN(NTOK / 4);
  const long long llDD = (long long)DD, llTD = (long long)TD;

  // ---- one-time prep (6 launches) ----
  padmask2_kernel<<<dim3(SEQ / 64, BATCH, 2), dim3(64), 0, stream>>>(src, tgt, pmS, pmT);
  tconv3_kernel<<<dim3(8, 8, 72), blk, 0, stream>>>(enc_attn_w, dec_self_w, dec_src_w, wt_enc_attn);
  tconv2_kernel<<<dim3(32, 8, 12), blk, 0, stream>>>(enc_ff_w1, dec_ff_w1, wt_enc_ff1, wt_dec_ff1, 6, 512, 2048);
  tconv2_kernel<<<dim3(8, 32, 12), blk, 0, stream>>>(enc_ff_w2, dec_ff_w2, wt_enc_ff2, wt_dec_ff2, 6, 2048, 512);
  tconv2_kernel<<<dim3(500, 8, 1), blk, 0, stream>>>(fc_w, fc_w, fcwt, fcwt, 1, 512, VOCAB);
  embed2_kernel<<<dim3(2048, 2), blk, 0, stream>>>(src, tgt, src_emb, tgt_emb, pe, xe, yd);

  // ---- encoder ----
  for (int l = 0; l < NLAYER; ++l) {
    ln_kernel<<<gLN, blk, 0, stream>>>(xe, enc_ln_g + (size_t)(l * 2 + 0) * D_MODEL,
                                       enc_ln_bb + (size_t)(l * 2 + 0) * D_MODEL, x2b);
    mm_kernel<4, 64, 64, 0><<<gQKV, blk, 0, stream>>>(x2b, wt_enc_attn + (size_t)l * 4 * DD,
        enc_attn_b + (size_t)l * 4 * D_MODEL, nullptr, qb, vtb, NTOK, 512, 512, llDD, D_MODEL, llTD);
    fattn_kernel<0, 0><<<gAttn, blkA, 0, stream>>>(qb, kb, vtb, nullptr, nullptr, pmS, aob);
    mm_kernel<1, 64, 32, 0><<<gN512, blk, 0, stream>>>(aob, wt_enc_attn + (size_t)(l * 4 + 3) * DD,
        enc_attn_b + (size_t)(l * 4 + 3) * D_MODEL, xe, xe, nullptr, NTOK, 512, 512, 0, 0, 0);
    ln_kernel<<<gLN, blk, 0, stream>>>(xe, enc_ln_g + (size_t)(l * 2 + 1) * D_MODEL,
                                       enc_ln_bb + (size_t)(l * 2 + 1) * D_MODEL, x2b);
    mm_kernel<3, 64, 64, 0><<<gFF1, blk, 0, stream>>>(x2b, wt_enc_ff1 + (size_t)l * FD,
        enc_ff_b1 + (size_t)l * DFF_, nullptr, hbb, nullptr, NTOK, DFF_, 512, 0, 0, 0);
    if (l == NLAYER - 1)
      mm_kernel<6, 64, 32, 0><<<gN512, blk, 0, stream>>>(hbb, wt_enc_ff2 + (size_t)l * FD,
          enc_ff_b2 + (size_t)l * D_MODEL, xe, xe, memb, NTOK, 512, DFF_, 0, 0, 0);
    else
      mm_kernel<1, 64, 32, 0><<<gN512, blk, 0, stream>>>(hbb, wt_enc_ff2 + (size_t)l * FD,
          enc_ff_b2 + (size_t)l * D_MODEL, xe, xe, nullptr, NTOK, 512, DFF_, 0, 0, 0);
  }

  // ---- all 6 decoder layers' cross K / V^T in one batched launch ----
  mm_kernel<5, 64, 64, 1><<<gCKV, blk, 0, stream>>>(memb, wt_dec_src, dec_src_b, nullptr,
      ckb, cvtb, NTOK, 512, 512, 0, 0, llTD);

  // ---- decoder ----
  for (int l = 0; l < NLAYER; ++l) {
    const u16* Ws = wt_dec_self + (size_t)l * 4 * DD;
    const u16* Wc = wt_dec_src + (size_t)l * 4 * DD;
    const float* bs  = dec_self_b + (size_t)l * 4 * D_MODEL;
    const float* bcb = dec_src_b + (size_t)l * 4 * D_MODEL;
    // self-attention (causal + tgt pad mask)
    ln_kernel<<<gLN, blk, 0, stream>>>(yd, dec_ln_g + (size_t)(l * 3 + 0) * D_MODEL,
                                       dec_ln_bb + (size_t)(l * 3 + 0) * D_MODEL, x2b);
    mm_kernel<4, 64, 64, 0><<<gQKV, blk, 0, stream>>>(x2b, Ws, bs, nullptr, qb, vtb,
                                                      NTOK, 512, 512, llDD, D_MODEL, llTD);
    fattn_kernel<1, 0><<<gAttn, blkA, 0, stream>>>(qb, kb, vtb, nullptr, nullptr, pmT, aob);
    mm_kernel<1, 64, 32, 0><<<gN512, blk, 0, stream>>>(aob, Ws + 3 * DD, bs + 3 * D_MODEL, yd, yd,
                                                       nullptr, NTOK, 512, 512, 0, 0, 0);
    // cross-attention (src pad mask); K/V precomputed, Q projected in-kernel
    ln_kernel<<<gLN, blk, 0, stream>>>(yd, dec_ln_g + (size_t)(l * 3 + 1) * D_MODEL,
                                       dec_ln_bb + (size_t)(l * 3 + 1) * D_MODEL, x2b);
    fattn_kernel<0, 1><<<gAttn, blkA, 0, stream>>>(x2b, ckb + (size_t)l * TD, cvtb + (size_t)l * TD,
                                                   Wc, bcb, pmS, aob);
    mm_kernel<1, 64, 32, 0><<<gN512, blk, 0, stream>>>(aob, Wc + 3 * DD, bcb + 3 * D_MODEL, yd, yd,
                                                       nullptr, NTOK, 512, 512, 0, 0, 0);
    // feed-forward
    ln_kernel<<<gLN, blk, 0, stream>>>(yd, dec_ln_g + (size_t)(l * 3 + 2) * D_MODEL,
                                       dec_ln_bb + (size_t)(l * 3 + 2) * D_MODEL, x2b);
    mm_kernel<3, 64, 64, 0><<<gFF1, blk, 0, stream>>>(x2b, wt_dec_ff1 + (size_t)l * FD,
        dec_ff_b1 + (size_t)l * DFF_, nullptr, hbb, nullptr, NTOK, DFF_, 512, 0, 0, 0);
    mm_kernel<1, 64, 32, 0><<<gN512, blk, 0, stream>>>(hbb, wt_dec_ff2 + (size_t)l * FD,
        dec_ff_b2 + (size_t)l * D_MODEL, yd, yd, nullptr, NTOK, 512, DFF_, 0, 0, 0);
  }

  // ---- head ----
  ln_kernel<<<gLN, blk, 0, stream>>>(yd, fin_ln_g, fin_ln_b, x2b);
  mm_kernel<0, 128, 256, 0, 1><<<gFC, blk, 0, stream>>>(x2b, fcwt, fc_b, nullptr, out, nullptr,
                                                        NTOK, VOCAB, 512, 0, 0, 0);

  (void)in_sizes; (void)n_in; (void)out_size; (void)ws_size;
}

// Round 14
// 2212.583 us; speedup vs baseline: 1.0146x; 1.0146x over previous
//
#include <hip/hip_runtime.h>
#include <math.h>

#define D_MODEL 512
#define NHEAD   8
#define NLAYER  6
#define DFF_    2048
#define VOCAB   32000
#define BATCH   2
#define SEQ     2048
#define NTOK    (BATCH*SEQ)
#define PAD_ID  1

typedef __attribute__((ext_vector_type(8))) short s16x8;
typedef __attribute__((ext_vector_type(4))) float f32x4;
typedef unsigned short u16;
typedef unsigned int   u32;
typedef unsigned long long u64;

__device__ __forceinline__ u16 f2bf(float x) {
  u32 u = __builtin_bit_cast(u32, x);
  u += 0x7FFFu + ((u >> 16) & 1u);
  return (u16)(u >> 16);
}

__device__ __forceinline__ float exp2i(float x) {
  float r; asm("v_exp_f32 %0, %1" : "=v"(r) : "v"(x)); return r;
}

__device__ __forceinline__ void gload16(const void* g, void* l) {
  __builtin_amdgcn_global_load_lds(
      (const __attribute__((address_space(1))) u32*)g,
      (__attribute__((address_space(3))) u32*)l, 16, 0, 0);
}

#define CEXP 0.1803368802f   /* 0.125 * log2(e) */

// ------------------------------------------------------------------ embed both streams (z = 0 src, 1 tgt)
__global__ __launch_bounds__(256) void embed2_kernel(
    const int* __restrict__ src, const int* __restrict__ tgt,
    const float* __restrict__ se, const float* __restrict__ te,
    const float* __restrict__ pe, float* __restrict__ xe, float* __restrict__ yd)
{
  const int z = blockIdx.y;
  const int* tok = z ? tgt : src;
  const float* emb = z ? te : se;
  float* out = z ? yd : xe;
  const int total = NTOK * D_MODEL;
  for (int i = blockIdx.x * 256 + threadIdx.x; i < total; i += gridDim.x * 256) {
    int t = i >> 9;
    int d = i & 511;
    int s = t & (SEQ - 1);
    out[i] = emb[(size_t)tok[t] * D_MODEL + d] + pe[(size_t)s * D_MODEL + d];
  }
}

// ------------------------------------------------------------------ pad masks for both token streams
__global__ __launch_bounds__(64) void padmask2_kernel(
    const int* __restrict__ src, const int* __restrict__ tgt,
    u64* __restrict__ pmS, u64* __restrict__ pmT)
{
  const int z = blockIdx.z;
  const int* tok = z ? tgt : src;
  u64* pm = z ? pmT : pmS;
  int b = blockIdx.y, t = blockIdx.x;
  int lane = threadIdx.x;
  u64 m = __ballot(tok[(size_t)b * SEQ + t * 64 + lane] != PAD_ID);
  if (lane == 0) pm[b * (SEQ / 64) + t] = m;
}

// ------------------------------------------------------------------ layernorm: one wave per row, shuffle-only
__global__ __launch_bounds__(256) void ln_kernel(
    const float* __restrict__ x, const float* __restrict__ g,
    const float* __restrict__ bb, u16* __restrict__ y)
{
  const int lane = threadIdx.x & 63;
  const size_t row = (size_t)blockIdx.x * 4 + (threadIdx.x >> 6);
  const float* xr = x + row * D_MODEL + lane * 8;
  float4 v0 = *(const float4*)xr;
  float4 v1 = *(const float4*)(xr + 4);
  float sum = (v0.x + v0.y) + (v0.z + v0.w) + (v1.x + v1.y) + (v1.z + v1.w);
  float ss = v0.x * v0.x + v0.y * v0.y + v0.z * v0.z + v0.w * v0.w
           + v1.x * v1.x + v1.y * v1.y + v1.z * v1.z + v1.w * v1.w;
  #pragma unroll
  for (int o = 1; o < 64; o <<= 1) {
    sum += __shfl_xor(sum, o, 64);
    ss  += __shfl_xor(ss, o, 64);
  }
  float mean = sum * (1.0f / D_MODEL);
  float inv = rsqrtf(ss * (1.0f / D_MODEL) - mean * mean + 1e-5f);
  float4 g0 = *(const float4*)&g[lane * 8];
  float4 g1 = *(const float4*)&g[lane * 8 + 4];
  float4 c0 = *(const float4*)&bb[lane * 8];
  float4 c1 = *(const float4*)&bb[lane * 8 + 4];
  uint4 o;
  o.x = (u32)f2bf((v0.x - mean) * inv * g0.x + c0.x) | ((u32)f2bf((v0.y - mean) * inv * g0.y + c0.y) << 16);
  o.y = (u32)f2bf((v0.z - mean) * inv * g0.z + c0.z) | ((u32)f2bf((v0.w - mean) * inv * g0.w + c0.w) << 16);
  o.z = (u32)f2bf((v1.x - mean) * inv * g1.x + c1.x) | ((u32)f2bf((v1.y - mean) * inv * g1.y + c1.y) << 16);
  o.w = (u32)f2bf((v1.z - mean) * inv * g1.z + c1.z) | ((u32)f2bf((v1.w - mean) * inv * g1.w + c1.w) << 16);
  *(uint4*)&y[row * D_MODEL + lane * 8] = o;
}

// ------------------------------------------------------------------ transpose+convert, two-source: f32 [K][N] -> bf16 [N][K]
__global__ __launch_bounds__(256) void tconv2_kernel(
    const float* __restrict__ s0, const float* __restrict__ s1,
    u16* __restrict__ d0, u16* __restrict__ d1, int zsplit, int K, int N)
{
  __shared__ float tile[64][65];
  const int z = blockIdx.z;
  const float* src = (z < zsplit) ? s0 + (size_t)z * K * N : s1 + (size_t)(z - zsplit) * K * N;
  u16* dst = (z < zsplit) ? d0 + (size_t)z * K * N : d1 + (size_t)(z - zsplit) * K * N;
  const int n0 = blockIdx.x * 64, k0 = blockIdx.y * 64;
  const int t = threadIdx.x;
  const int cr = t >> 4, cc = (t & 15) * 4;
  #pragma unroll
  for (int it = 0; it < 4; ++it) {
    int kr = cr + it * 16;
    float4 v = *(const float4*)&src[(size_t)(k0 + kr) * N + n0 + cc];
    tile[kr][cc] = v.x; tile[kr][cc + 1] = v.y; tile[kr][cc + 2] = v.z; tile[kr][cc + 3] = v.w;
  }
  __syncthreads();
  #pragma unroll
  for (int it = 0; it < 4; ++it) {
    int nr = cr + it * 16;
    u32 lo = (u32)f2bf(tile[cc + 0][nr]) | ((u32)f2bf(tile[cc + 1][nr]) << 16);
    u32 hi = (u32)f2bf(tile[cc + 2][nr]) | ((u32)f2bf(tile[cc + 3][nr]) << 16);
    uint2 pk; pk.x = lo; pk.y = hi;
    *(uint2*)&dst[(size_t)(n0 + nr) * K + k0 + cc] = pk;
  }
}

// ------------------------------------------------------------------ transpose+convert, three-source 512x512 (z: 0-23 s0, 24-47 s1, 48-71 s2)
__global__ __launch_bounds__(256) void tconv3_kernel(
    const float* __restrict__ s0, const float* __restrict__ s1,
    const float* __restrict__ s2, u16* __restrict__ dst0)
{
  __shared__ float tile[64][65];
  const int z = blockIdx.z;
  const float* src = (z < 24) ? s0 + (size_t)z * 262144
                   : (z < 48) ? s1 + (size_t)(z - 24) * 262144
                              : s2 + (size_t)(z - 48) * 262144;
  u16* dst = dst0 + (size_t)z * 262144;
  const int n0 = blockIdx.x * 64, k0 = blockIdx.y * 64;
  const int t = threadIdx.x;
  const int cr = t >> 4, cc = (t & 15) * 4;
  #pragma unroll
  for (int it = 0; it < 4; ++it) {
    int kr = cr + it * 16;
    float4 v = *(const float4*)&src[(size_t)(k0 + kr) * 512 + n0 + cc];
    tile[kr][cc] = v.x; tile[kr][cc + 1] = v.y; tile[kr][cc + 2] = v.z; tile[kr][cc + 3] = v.w;
  }
  __syncthreads();
  #pragma unroll
  for (int it = 0; it < 4; ++it) {
    int nr = cr + it * 16;
    u32 lo = (u32)f2bf(tile[cc + 0][nr]) | ((u32)f2bf(tile[cc + 1][nr]) << 16);
    u32 hi = (u32)f2bf(tile[cc + 2][nr]) | ((u32)f2bf(tile[cc + 3][nr]) << 16);
    uint2 pk; pk.x = lo; pk.y = hi;
    *(uint2*)&dst[(size_t)(n0 + nr) * 512 + k0 + cc] = pk;
  }
}

// ------------------------------------------------------------------ bf16 MFMA GEMM: C[M,N] = A[M,K] @ Wt[N,K]^T + bias
// MODE 0: f32 out, 1: f32 out + res, 2: bf16 out, 3: bf16 out + relu,
// MODE 4: qkv (z==2 -> V-transpose into vtOut), 5: crosskv (MAP=1; odd z -> vtrans),
// MODE 6: f32 out + res + bf16 row-major copy into vtOut
// DB (BM+BN<=256): double-buffered LDS, 1 barrier/K-step.
// XSWAP: blockIdx.x indexes M (consecutive blocks share the B-tile).
template<int MODE, int BM, int BN, int MAP, int XSWAP = 0>
__global__ __launch_bounds__(256, 2) void mm_kernel(
    const u16* __restrict__ A, const u16* __restrict__ Wt,
    const float* __restrict__ bias, const float* __restrict__ res,
    void* __restrict__ Cout, u16* __restrict__ vtOut,
    int M, int N, int K,
    long long wStride, long long bStride, long long cStride)
{
  constexpr int MI = BM / 32;
  constexpr int NI = (BN + 31) / 32;          // 1 for BN=32
  constexpr int NFRAG = (BN >= 32) ? NI : 1;
  constexpr bool DB = (BM + BN <= 256);
  __shared__ u16 sh[(DB ? 2 : 1) * (BM + BN) * 64];
  const int z = blockIdx.z;
  size_t wOff, bOff;
  if (MAP == 1) {
    wOff = (size_t)(z >> 1) * 4 * 262144 + (size_t)(1 + (z & 1)) * 262144;
    bOff = (size_t)(z >> 1) * 4 * 512 + (size_t)(1 + (z & 1)) * 512;
  } else {
    wOff = (size_t)z * wStride;
    bOff = (size_t)z * bStride;
  }
  Wt += wOff;
  bias += bOff;
  const int bm = (XSWAP ? blockIdx.x : blockIdx.y) * BM;
  const int bn = (XSWAP ? blockIdx.y : blockIdx.x) * BN;
  const int tid = threadIdx.x, lane = tid & 63, w = tid >> 6;
  const int wm = w >> 1, wn = w & 1;
  const int l15 = lane & 15, l4 = lane >> 4;
  const int wrow0 = wm * (BM / 2), wcol0 = wn * (BN / 2);
  const u16* aBase = A  + (size_t)bm * K;
  const u16* bBase = Wt + (size_t)bn * K;
  f32x4 acc[MI][NFRAG] = {};

  auto mfma_step = [&](const u16* Asb, const u16* Bsb) {
    #pragma unroll
    for (int ks = 0; ks < 2; ++ks) {
      s16x8 af[MI], bf[NFRAG];
      #pragma unroll
      for (int mi = 0; mi < MI; ++mi) {
        int rr = wrow0 + mi * 16 + l15;
        af[mi] = *(const s16x8*)&Asb[(rr << 6) + (((ks * 4 + l4) ^ (rr & 7)) << 3)];
      }
      #pragma unroll
      for (int ni = 0; ni < NFRAG; ++ni) {
        int rr = wcol0 + ni * 16 + l15;
        bf[ni] = *(const s16x8*)&Bsb[(rr << 6) + (((ks * 4 + l4) ^ (rr & 7)) << 3)];
      }
      #pragma unroll
      for (int mi = 0; mi < MI; ++mi)
        #pragma unroll
        for (int ni = 0; ni < NFRAG; ++ni)
          acc[mi][ni] = __builtin_amdgcn_mfma_f32_16x16x32_bf16(af[mi], bf[ni], acc[mi][ni], 0, 0, 0);
    }
  };

  if constexpr (DB) {
    u16* As0 = sh;
    u16* As1 = sh + BM * 64;
    u16* Bs0 = sh + 2 * BM * 64;
    u16* Bs1 = sh + 2 * BM * 64 + BN * 64;
    auto stage = [&](int k0, u16* Ad, u16* Bd) {
      #pragma unroll
      for (int i = 0; i < BM / 32; ++i) {
        int lin = i * 256 + tid;
        int r = lin >> 3, sp = lin & 7;
        gload16(aBase + (size_t)r * K + k0 + ((sp ^ (r & 7)) * 8), &Ad[(i * 256 + w * 64) * 8]);
      }
      if constexpr (BN >= 64) {
        #pragma unroll
        for (int i = 0; i < BN / 32; ++i) {
          int lin = i * 256 + tid;
          int r = lin >> 3, sp = lin & 7;
          gload16(bBase + (size_t)r * K + k0 + ((sp ^ (r & 7)) * 8), &Bd[(i * 256 + w * 64) * 8]);
        }
      } else {
        int r = tid >> 3, sp = tid & 7;   // 256 threads cover 32 rows x 64 k
        gload16(bBase + (size_t)r * K + k0 + ((sp ^ (r & 7)) * 8), &Bd[(w * 64) * 8]);
      }
    };
    stage(0, As0, Bs0);
    __syncthreads();
    const int nt = K >> 6;
    for (int t = 0; t < nt; ++t) {
      const bool even = !(t & 1);
      u16* Ac = even ? As0 : As1;
      u16* Bc = even ? Bs0 : Bs1;
      if (t + 1 < nt) stage((t + 1) << 6, even ? As1 : As0, even ? Bs1 : Bs0);
      mfma_step(Ac, Bc);
      __syncthreads();
    }
  } else {
    u16* As = sh;
    u16* Bs = sh + BM * 64;
    for (int k0 = 0; k0 < K; k0 += 64) {
      #pragma unroll
      for (int i = 0; i < BM / 32; ++i) {
        int lin = i * 256 + tid;
        int r = lin >> 3, sp = lin & 7;
        gload16(aBase + (size_t)r * K + k0 + ((sp ^ (r & 7)) * 8), &As[(i * 256 + w * 64) * 8]);
      }
      #pragma unroll
      for (int i = 0; i < BN / 32; ++i) {
        int lin = i * 256 + tid;
        int r = lin >> 3, sp = lin & 7;
        gload16(bBase + (size_t)r * K + k0 + ((sp ^ (r & 7)) * 8), &Bs[(i * 256 + w * 64) * 8]);
      }
      __syncthreads();
      mfma_step(As, Bs);
      __syncthreads();
    }
  }

  const bool vpath = (MODE == 4 && z == 2) || (MODE == 5 && (z & 1) == 1);
  if (vpath) {
    u16* TT = sh;
    #pragma unroll
    for (int mi = 0; mi < MI; ++mi)
      #pragma unroll
      for (int ni = 0; ni < NFRAG; ++ni)
        #pragma unroll
        for (int r = 0; r < 4; ++r) {
          int rowl = wrow0 + mi * 16 + l4 * 4 + r;
          int coll = wcol0 + ni * 16 + l15;
          TT[coll * 72 + rowl] = f2bf(acc[mi][ni][r] + bias[bn + coll]);
        }
    __syncthreads();
    const int b = bm >> 11, s0loc = bm & 2047, h = bn >> 6;
    const int layer = (MODE == 5) ? (z >> 1) : 0;
    u16* vbase = vtOut + (size_t)layer * ((size_t)NTOK * D_MODEL)
               + ((size_t)(b * NHEAD + h) * 64) * SEQ;
    int d = tid >> 2, sc = (tid & 3) * 16;
    s16x8 v0 = *(const s16x8*)&TT[d * 72 + sc];
    s16x8 v1 = *(const s16x8*)&TT[d * 72 + sc + 8];
    *(s16x8*)(vbase + (size_t)d * SEQ + s0loc + sc) = v0;
    *(s16x8*)(vbase + (size_t)d * SEQ + s0loc + sc + 8) = v1;
    return;
  }

  const int zi = (MAP == 1) ? (z >> 1) : z;
  #pragma unroll
  for (int ni = 0; ni < NFRAG; ++ni) {
    int col = bn + wcol0 + ni * 16 + l15;
    float bb = bias[col];
    #pragma unroll
    for (int mi = 0; mi < MI; ++mi) {
      #pragma unroll
      for (int r = 0; r < 4; ++r) {
        int row = bm + wrow0 + mi * 16 + l4 * 4 + r;
        size_t off = (size_t)zi * cStride + (size_t)row * N + col;
        float v = acc[mi][ni][r] + bb;
        if (MODE == 1 || MODE == 6) v += res[(size_t)row * N + col];
        if (MODE == 3) v = fmaxf(v, 0.0f);
        if (MODE <= 1 || MODE == 6) ((float*)Cout)[off] = v;
        else                        ((u16*)Cout)[off] = f2bf(v);
        if (MODE == 6) vtOut[(size_t)row * N + col] = f2bf(v);
      }
    }
  }
}

// ------------------------------------------------------------------ flash attention, bf16 MFMA
// QBLK=128 (8 waves, 512 threads; wave w owns q-rows qt+16w..+16), KVBLK=128,
// double-buffered K/V. Swapped QK^T: each thread owns one q-row.
template<int CAUSAL, int QPROJ>
__global__ __launch_bounds__(512, 2) void fattn_kernel(
    const u16* __restrict__ Qg, const u16* __restrict__ Kg,
    const u16* __restrict__ Vt, const u16* __restrict__ Wq,
    const float* __restrict__ qbias, const u64* __restrict__ padm,
    u16* __restrict__ Og)
{
  __shared__ u16 Ks[2][128 * 64];
  __shared__ u16 Vs[2][64 * 128];
  __shared__ u16 Ps[8][16 * 128];
  const int qtile = CAUSAL ? (int)(gridDim.x - 1 - blockIdx.x) : (int)blockIdx.x;
  const int qt = qtile * 128;
  const int h = blockIdx.y, b = blockIdx.z;
  const int tid = threadIdx.x, lane = tid & 63, w = tid >> 6;   // w in [0,8)
  const int l15 = lane & 15, l4 = lane >> 4;
  const int hoff = h * 64;
  const u16* Kbase = Kg + (size_t)(b * SEQ) * D_MODEL + hoff;
  const u16* Vbase = Vt + (size_t)(b * NHEAD + h) * 64 * SEQ;
  const u64* pmb = padm + b * (SEQ / 64);
  const int qg = qt + w * 16 + l15;    // this thread's q row

  s16x8 aq[2];
  if constexpr (QPROJ) {
    // Q[128x64] = X[qt..qt+128, :] @ Wq[h*64..+64, :]^T + qbias
    const u16* xBase = Qg + (size_t)(b * SEQ + qt) * D_MODEL;
    const u16* wBase = Wq + (size_t)hoff * D_MODEL;
    u16* Xs  = Ks[0];            // 128x64 = 16 KB
    u16* Wsh = Vs[0];            // 64x64  =  8 KB
    f32x4 qa[4] = {};
    for (int k0 = 0; k0 < 512; k0 += 64) {
      #pragma unroll
      for (int i = 0; i < 2; ++i) {
        int lin = i * 512 + tid;
        int r = lin >> 3, sp = lin & 7;
        gload16(xBase + (size_t)r * D_MODEL + k0 + ((sp ^ (r & 7)) * 8), &Xs[(i * 512 + w * 64) * 8]);
      }
      {
        int r = tid >> 3, sp = tid & 7;
        gload16(wBase + (size_t)r * D_MODEL + k0 + ((sp ^ (r & 7)) * 8), &Wsh[(w * 64) * 8]);
      }
      __syncthreads();
      #pragma unroll
      for (int ks = 0; ks < 2; ++ks) {
        int rr = w * 16 + l15;
        s16x8 xa = *(const s16x8*)&Xs[(rr << 6) + (((ks * 4 + l4) ^ (rr & 7)) << 3)];
        #pragma unroll
        for (int ni = 0; ni < 4; ++ni) {
          int rw = ni * 16 + l15;
          s16x8 wb = *(const s16x8*)&Wsh[(rw << 6) + (((ks * 4 + l4) ^ (rw & 7)) << 3)];
          qa[ni] = __builtin_amdgcn_mfma_f32_16x16x32_bf16(xa, wb, qa[ni], 0, 0, 0);
        }
      }
      __syncthreads();
    }
    // C-layout -> A-layout transpose through swizzled LDS (16 KB of Ps)
    u16* Qsh = (u16*)Ps;
    #pragma unroll
    for (int ni = 0; ni < 4; ++ni) {
      int col = ni * 16 + l15;
      float bb = qbias[hoff + col];
      #pragma unroll
      for (int r = 0; r < 4; ++r) {
        int row = w * 16 + l4 * 4 + r;
        Qsh[(row << 6) + ((((col >> 3)) ^ (row & 7)) << 3) + (col & 7)] = f2bf(qa[ni][r] + bb);
      }
    }
    __syncthreads();
    {
      int rr = w * 16 + l15;
      aq[0] = *(const s16x8*)&Qsh[(rr << 6) + (((0 + l4) ^ (rr & 7)) << 3)];
      aq[1] = *(const s16x8*)&Qsh[(rr << 6) + (((4 + l4) ^ (rr & 7)) << 3)];
    }
  } else {
    const u16* qp = Qg + (size_t)(b * SEQ + qg) * D_MODEL + hoff + l4 * 8;
    aq[0] = *(const s16x8*)qp;
    aq[1] = *(const s16x8*)(qp + 32);
  }

  f32x4 oacc[4] = {};            // oacc[jn][r] = O[q][d = jn*16 + l4*4 + r]
  float mrow = -1e30f, lrow = 0.f;
  const int nt = CAUSAL ? (qt >> 7) + 1 : SEQ / 128;

  #define STAGE(KV0, BUF)                                                              \
    {                                                                                  \
      _Pragma("unroll")                                                                \
      for (int it = 0; it < 2; ++it) {                                                 \
        int lin = it * 512 + tid;                                                      \
        int rr = lin >> 3, sp = lin & 7;                                               \
        gload16(Kbase + (size_t)((KV0) + rr) * D_MODEL + ((sp ^ (rr & 7)) * 8),        \
                &Ks[BUF][(it * 512 + w * 64) * 8]);                                    \
      }                                                                                \
      _Pragma("unroll")                                                                \
      for (int it = 0; it < 2; ++it) {                                                 \
        int lin = it * 512 + tid;                                                      \
        int rr = lin >> 4, ko = lin & 15;                                              \
        gload16(Vbase + (size_t)rr * SEQ + (KV0) + ((ko ^ (rr & 15)) * 8),             \
                &Vs[BUF][(it * 512 + w * 64) * 8]);                                    \
      }                                                                                \
    }

  if constexpr (QPROJ) __syncthreads();   // aq reads done before Ks/Vs/Ps reuse
  STAGE(0, 0);
  __syncthreads();

  for (int kt = 0; kt < nt; ++kt) {
    const int kv0 = kt * 128;
    const int cur = kt & 1;
    if (kt + 1 < nt) STAGE(kv0 + 128, cur ^ 1);

    // S^T[kv][q] = mfma(K, Q): sac[jn][r] -> kv = kv0 + jn*16 + l4*4 + r, q = l15
    f32x4 sac[8] = {};
    __builtin_amdgcn_s_setprio(1);
    #pragma unroll
    for (int ks = 0; ks < 2; ++ks)
      #pragma unroll
      for (int jn = 0; jn < 8; ++jn) {
        int rr = jn * 16 + l15;
        s16x8 ak = *(const s16x8*)&Ks[cur][(rr << 6) + (((ks * 4 + l4) ^ (rr & 7)) << 3)];
        sac[jn] = __builtin_amdgcn_mfma_f32_16x16x32_bf16(ak, aq[ks], sac[jn], 0, 0, 0);
      }
    __builtin_amdgcn_s_setprio(0);

    const u64 m0 = pmb[(kv0 >> 6)];
    const u64 m1 = pmb[(kv0 >> 6) + 1];
    const bool lastC = CAUSAL && (kt == nt - 1);
    if (((m0 & m1) != ~0ull) || lastC) {
      #pragma unroll
      for (int jn = 0; jn < 8; ++jn) {
        u64 mm = (jn < 4) ? m0 : m1;
        #pragma unroll
        for (int r = 0; r < 4; ++r) {
          int kl = (jn & 3) * 16 + l4 * 4 + r;
          int kvg = kv0 + jn * 16 + l4 * 4 + r;
          bool ok = ((mm >> kl) & 1) && (!CAUSAL || kvg <= qg);
          if (!ok) sac[jn][r] = -1e30f;
        }
      }
    }

    // row max: thread-local over 32, then 2 shuffles across l4
    float m = sac[0][0];
    #pragma unroll
    for (int jn = 0; jn < 8; ++jn)
      #pragma unroll
      for (int r = 0; r < 4; ++r) m = fmaxf(m, sac[jn][r]);
    m = fmaxf(m, __shfl_xor(m, 16, 64));
    m = fmaxf(m, __shfl_xor(m, 32, 64));

    if (__any(m - mrow > 64.0f)) {    // defer-max (THR = 8 post-scale)
      float mn = fmaxf(mrow, m);
      float sc = exp2i((mrow - mn) * CEXP);
      mrow = mn;
      lrow *= sc;
      #pragma unroll
      for (int jn = 0; jn < 4; ++jn)
        #pragma unroll
        for (int r = 0; r < 4; ++r) oacc[jn][r] *= sc;
    }

    // P = exp; pack 4 bf16 -> b64 LDS store (swizzled), accumulate row sum
    float rs = 0.f;
    #pragma unroll
    for (int jn = 0; jn < 8; ++jn) {
      float p0 = exp2i((sac[jn][0] - mrow) * CEXP);
      float p1 = exp2i((sac[jn][1] - mrow) * CEXP);
      float p2 = exp2i((sac[jn][2] - mrow) * CEXP);
      float p3 = exp2i((sac[jn][3] - mrow) * CEXP);
      rs += (p0 + p1) + (p2 + p3);
      uint2 pk;
      pk.x = (u32)f2bf(p0) | ((u32)f2bf(p1) << 16);
      pk.y = (u32)f2bf(p2) | ((u32)f2bf(p3) << 16);
      int pu = (jn * 4 + l4) ^ ((l15 & 7) << 2);
      *(uint2*)&Ps[w][l15 * 128 + pu * 4] = pk;
    }
    rs += __shfl_xor(rs, 16, 64);
    rs += __shfl_xor(rs, 32, 64);
    lrow += rs;

    // O^T accumulation: oacc[jn] = mfma(A = V^T[d-block jn], B = P^T)
    __builtin_amdgcn_s_setprio(1);
    #pragma unroll
    for (int ks2 = 0; ks2 < 4; ++ks2) {
      int pu = (ks2 * 8 + l4 * 2) ^ ((l15 & 7) << 2);
      s16x8 pb = *(const s16x8*)&Ps[w][l15 * 128 + pu * 4];
      #pragma unroll
      for (int jn = 0; jn < 4; ++jn) {
        int rr = jn * 16 + l15;
        s16x8 av = *(const s16x8*)&Vs[cur][(rr << 7) + (((ks2 * 4 + l4) ^ (rr & 15)) << 3)];
        oacc[jn] = __builtin_amdgcn_mfma_f32_16x16x32_bf16(av, pb, oacc[jn], 0, 0, 0);
      }
    }
    __builtin_amdgcn_s_setprio(0);
    __syncthreads();
  }
  #undef STAGE

  const float inv = 1.0f / lrow;
  u16* orow = Og + (size_t)(b * SEQ + qg) * D_MODEL + hoff;
  #pragma unroll
  for (int jn = 0; jn < 4; ++jn) {
    uint2 pk;
    pk.x = (u32)f2bf(oacc[jn][0] * inv) | ((u32)f2bf(oacc[jn][1] * inv) << 16);
    pk.y = (u32)f2bf(oacc[jn][2] * inv) | ((u32)f2bf(oacc[jn][3] * inv) << 16);
    *(uint2*)(orow + jn * 16 + l4 * 4) = pk;
  }
}

// ------------------------------------------------------------------ host
extern "C" void kernel_launch(void* const* d_in, const int* in_sizes, int n_in,
                              void* d_out, int out_size, void* d_ws, size_t ws_size,
                              hipStream_t stream)
{
  const int*   src        = (const int*)  d_in[0];
  const int*   tgt        = (const int*)  d_in[1];
  const float* src_emb    = (const float*)d_in[2];
  const float* tgt_emb    = (const float*)d_in[3];
  const float* pe         = (const float*)d_in[4];
  const float* enc_attn_w = (const float*)d_in[5];
  const float* enc_attn_b = (const float*)d_in[6];
  const float* enc_ff_w1  = (const float*)d_in[7];
  const float* enc_ff_b1  = (const float*)d_in[8];
  const float* enc_ff_w2  = (const float*)d_in[9];
  const float* enc_ff_b2  = (const float*)d_in[10];
  const float* enc_ln_g   = (const float*)d_in[11];
  const float* enc_ln_bb  = (const float*)d_in[12];
  const float* dec_self_w = (const float*)d_in[13];
  const float* dec_self_b = (const float*)d_in[14];
  const float* dec_src_w  = (const float*)d_in[15];
  const float* dec_src_b  = (const float*)d_in[16];
  const float* dec_ff_w1  = (const float*)d_in[17];
  const float* dec_ff_b1  = (const float*)d_in[18];
  const float* dec_ff_w2  = (const float*)d_in[19];
  const float* dec_ff_b2  = (const float*)d_in[20];
  const float* dec_ln_g   = (const float*)d_in[21];
  const float* dec_ln_bb  = (const float*)d_in[22];
  const float* fin_ln_g   = (const float*)d_in[23];
  const float* fin_ln_b   = (const float*)d_in[24];
  const float* fc_w       = (const float*)d_in[25];
  const float* fc_b       = (const float*)d_in[26];
  float* out = (float*)d_out;

  const size_t DD = (size_t)D_MODEL * D_MODEL;
  const size_t FD = (size_t)D_MODEL * DFF_;
  const size_t TD = (size_t)NTOK * D_MODEL;

  // ---- scratch in d_out (all dead before the final GEMM writes d_out) ----
  char* ob = (char*)d_out;
  size_t off = 0;
  auto alloco = [&](size_t bytes) { void* p = ob + off; off += (bytes + 255) & ~(size_t)255; return p; };
  u16* wt_enc_attn = (u16*)alloco(24 * DD * 2);
  u16* wt_dec_self = (u16*)alloco(24 * DD * 2);
  u16* wt_dec_src  = (u16*)alloco(24 * DD * 2);
  u16* wt_enc_ff1  = (u16*)alloco(6 * FD * 2);
  u16* wt_enc_ff2  = (u16*)alloco(6 * FD * 2);
  u16* wt_dec_ff1  = (u16*)alloco(6 * FD * 2);
  u16* wt_dec_ff2  = (u16*)alloco(6 * FD * 2);
  u16* qb   = (u16*)alloco(2 * TD * 2);             // q,k contiguous
  u16* kb   = qb + TD;
  u16* vtb  = (u16*)alloco(TD * 2);                 // self-attn V^T [B*H][64][SEQ]
  u16* aob  = (u16*)alloco(TD * 2);
  u16* hbb  = (u16*)alloco((size_t)NTOK * DFF_ * 2);
  u16* memb = (u16*)alloco(TD * 2);
  u16* ckb  = (u16*)alloco(6 * TD * 2);             // cross K, all layers
  u16* cvtb = (u16*)alloco(6 * TD * 2);             // cross V^T, all layers

  // ---- mandatory ws (live during final GEMM) ----
  char* wsb = (char*)d_ws;
  u16*   fcwt = (u16*)wsb;
  size_t wo = ((size_t)VOCAB * D_MODEL * 2 + 255) & ~(size_t)255;
  float* xe  = (float*)(wsb + wo); wo += TD * 4;
  float* yd  = (float*)(wsb + wo); wo += TD * 4;
  u16*   x2b = (u16*)(wsb + wo);   wo += TD * 2;
  u64*   pmS = (u64*)(wsb + wo);   wo += 1024;
  u64*   pmT = (u64*)(wsb + wo);

  dim3 blk(256), blkA(512);
  dim3 gN512(16, 64, 1), gQKV(8, 64, 3), gCKV(8, 64, 12);
  dim3 gFF1(16, 32, 1), gFC(32, 125, 1);
  dim3 gAttn(SEQ / 128, NHEAD, BATCH);
  dim3 gLN(NTOK / 4);
  const long long llDD = (long long)DD, llTD = (long long)TD;

  // ---- one-time prep (6 launches) ----
  padmask2_kernel<<<dim3(SEQ / 64, BATCH, 2), dim3(64), 0, stream>>>(src, tgt, pmS, pmT);
  tconv3_kernel<<<dim3(8, 8, 72), blk, 0, stream>>>(enc_attn_w, dec_self_w, dec_src_w, wt_enc_attn);
  tconv2_kernel<<<dim3(32, 8, 12), blk, 0, stream>>>(enc_ff_w1, dec_ff_w1, wt_enc_ff1, wt_dec_ff1, 6, 512, 2048);
  tconv2_kernel<<<dim3(8, 32, 12), blk, 0, stream>>>(enc_ff_w2, dec_ff_w2, wt_enc_ff2, wt_dec_ff2, 6, 2048, 512);
  tconv2_kernel<<<dim3(500, 8, 1), blk, 0, stream>>>(fc_w, fc_w, fcwt, fcwt, 1, 512, VOCAB);
  embed2_kernel<<<dim3(2048, 2), blk, 0, stream>>>(src, tgt, src_emb, tgt_emb, pe, xe, yd);

  // ---- encoder ----
  for (int l = 0; l < NLAYER; ++l) {
    ln_kernel<<<gLN, blk, 0, stream>>>(xe, enc_ln_g + (size_t)(l * 2 + 0) * D_MODEL,
                                       enc_ln_bb + (size_t)(l * 2 + 0) * D_MODEL, x2b);
    mm_kernel<4, 64, 64, 0><<<gQKV, blk, 0, stream>>>(x2b, wt_enc_attn + (size_t)l * 4 * DD,
        enc_attn_b + (size_t)l * 4 * D_MODEL, nullptr, qb, vtb, NTOK, 512, 512, llDD, D_MODEL, llTD);
    fattn_kernel<0, 0><<<gAttn, blkA, 0, stream>>>(qb, kb, vtb, nullptr, nullptr, pmS, aob);
    mm_kernel<1, 64, 32, 0><<<gN512, blk, 0, stream>>>(aob, wt_enc_attn + (size_t)(l * 4 + 3) * DD,
        enc_attn_b + (size_t)(l * 4 + 3) * D_MODEL, xe, xe, nullptr, NTOK, 512, 512, 0, 0, 0);
    ln_kernel<<<gLN, blk, 0, stream>>>(xe, enc_ln_g + (size_t)(l * 2 + 1) * D_MODEL,
                                       enc_ln_bb + (size_t)(l * 2 + 1) * D_MODEL, x2b);
    mm_kernel<3, 128, 128, 0><<<gFF1, blk, 0, stream>>>(x2b, wt_enc_ff1 + (size_t)l * FD,
        enc_ff_b1 + (size_t)l * DFF_, nullptr, hbb, nullptr, NTOK, DFF_, 512, 0, 0, 0);
    if (l == NLAYER - 1)
      mm_kernel<6, 64, 32, 0><<<gN512, blk, 0, stream>>>(hbb, wt_enc_ff2 + (size_t)l * FD,
          enc_ff_b2 + (size_t)l * D_MODEL, xe, xe, memb, NTOK, 512, DFF_, 0, 0, 0);
    else
      mm_kernel<1, 64, 32, 0><<<gN512, blk, 0, stream>>>(hbb, wt_enc_ff2 + (size_t)l * FD,
          enc_ff_b2 + (size_t)l * D_MODEL, xe, xe, nullptr, NTOK, 512, DFF_, 0, 0, 0);
  }

  // ---- all 6 decoder layers' cross K / V^T in one batched launch ----
  mm_kernel<5, 64, 64, 1><<<gCKV, blk, 0, stream>>>(memb, wt_dec_src, dec_src_b, nullptr,
      ckb, cvtb, NTOK, 512, 512, 0, 0, llTD);

  // ---- decoder ----
  for (int l = 0; l < NLAYER; ++l) {
    const u16* Ws = wt_dec_self + (size_t)l * 4 * DD;
    const u16* Wc = wt_dec_src + (size_t)l * 4 * DD;
    const float* bs  = dec_self_b + (size_t)l * 4 * D_MODEL;
    const float* bcb = dec_src_b + (size_t)l * 4 * D_MODEL;
    // self-attention (causal + tgt pad mask)
    ln_kernel<<<gLN, blk, 0, stream>>>(yd, dec_ln_g + (size_t)(l * 3 + 0) * D_MODEL,
                                       dec_ln_bb + (size_t)(l * 3 + 0) * D_MODEL, x2b);
    mm_kernel<4, 64, 64, 0><<<gQKV, blk, 0, stream>>>(x2b, Ws, bs, nullptr, qb, vtb,
                                                      NTOK, 512, 512, llDD, D_MODEL, llTD);
    fattn_kernel<1, 0><<<gAttn, blkA, 0, stream>>>(qb, kb, vtb, nullptr, nullptr, pmT, aob);
    mm_kernel<1, 64, 32, 0><<<gN512, blk, 0, stream>>>(aob, Ws + 3 * DD, bs + 3 * D_MODEL, yd, yd,
                                                       nullptr, NTOK, 512, 512, 0, 0, 0);
    // cross-attention (src pad mask); K/V precomputed, Q projected in-kernel
    ln_kernel<<<gLN, blk, 0, stream>>>(yd, dec_ln_g + (size_t)(l * 3 + 1) * D_MODEL,
                                       dec_ln_bb + (size_t)(l * 3 + 1) * D_MODEL, x2b);
    fattn_kernel<0, 1><<<gAttn, blkA, 0, stream>>>(x2b, ckb + (size_t)l * TD, cvtb + (size_t)l * TD,
                                                   Wc, bcb, pmS, aob);
    mm_kernel<1, 64, 32, 0><<<gN512, blk, 0, stream>>>(aob, Wc + 3 * DD, bcb + 3 * D_MODEL, yd, yd,
                                                       nullptr, NTOK, 512, 512, 0, 0, 0);
    // feed-forward
    ln_kernel<<<gLN, blk, 0, stream>>>(yd, dec_ln_g + (size_t)(l * 3 + 2) * D_MODEL,
                                       dec_ln_bb + (size_t)(l * 3 + 2) * D_MODEL, x2b);
    mm_kernel<3, 128, 128, 0><<<gFF1, blk, 0, stream>>>(x2b, wt_dec_ff1 + (size_t)l * FD,
        dec_ff_b1 + (size_t)l * DFF_, nullptr, hbb, nullptr, NTOK, DFF_, 512, 0, 0, 0);
    mm_kernel<1, 64, 32, 0><<<gN512, blk, 0, stream>>>(hbb, wt_dec_ff2 + (size_t)l * FD,
        dec_ff_b2 + (size_t)l * D_MODEL, yd, yd, nullptr, NTOK, 512, DFF_, 0, 0, 0);
  }

  // ---- head ----
  ln_kernel<<<gLN, blk, 0, stream>>>(yd, fin_ln_g, fin_ln_b, x2b);
  mm_kernel<0, 128, 256, 0, 1><<<gFC, blk, 0, stream>>>(x2b, fcwt, fc_b, nullptr, out, nullptr,
                                                        NTOK, VOCAB, 512, 0, 0, 0);

  (void)in_sizes; (void)n_in; (void)out_size; (void)ws_size;
}